// Round 9
// baseline (270.294 us; speedup 1.0000x reference)
//
#include <hip/hip_runtime.h>
#include <math.h>

// x:(4,16,256,128)f32  w_qkv:(128,384)  w_out:(128,128)  b_out:(128)  y:(4,16,256,128)f32
// Reshape map: J=pos>>7, d/e=(pos&127)*32+(c>>2), a=c&3.  Per (b,a) pair:
// flash attn seq=4096 dim=32, Q=(10*log2e)*l2norm4(k), K=V=M(v), M[e][J]=v.
// r9: swapped-operand attention (S^T = mfma(M_frag, Q_frag); softmax fully
// per-lane; P feeds PV directly) with PV expressed as 16x16x32 bf16 MFMAs
// (the only MFMA intrinsic used anywhere — proven in r2-r7). No LDS, no
// barriers, no per-iteration cross-lane ops in the attn main loop.
// Mpv2 within-64-block perm: pos = 32m + 8g + 4*h + r  holds  M[e][n] with
// e = 32m + 16h + 4g + r  ->  PV A-frag = contiguous bf16x8 at e0+32m+8g;
// PV B-frag = concat(pp[2m], pp[2m+1]) already in registers.
// ws (24MB): Qhi|Qlo [pair][d][J] bf16, Mhi|Mlo [pair][e][J] bf16,
//            Mpv2 [pair][n][e''] bf16, outb [row][chan] bf16.

#define SEQ 4096
#define PAIR_ELEMS (SEQ * 32)

typedef __attribute__((ext_vector_type(8))) short bf16x8;
typedef __attribute__((ext_vector_type(4))) float f32x4;

static __device__ __forceinline__ unsigned short f2bf(float x) {
    unsigned u = __float_as_uint(x);
    u += 0x7fffu + ((u >> 16) & 1u);
    return (unsigned short)(u >> 16);
}
static __device__ __forceinline__ float bf2f(unsigned short h) {
    return __uint_as_float(((unsigned)h) << 16);
}

// ---------------------------------------------------------------------------
// Kernel 1: k/v GEMM + in-thread l2norm + bf16 hi/lo split (r7/r8 structure).
// Only change vs r8: the Mpv2 scatter dst formula (new within-block perm).
// ---------------------------------------------------------------------------
__global__ __launch_bounds__(256) void kv_kernel(const float* __restrict__ x,
                                                 const float* __restrict__ wqkv,
                                                 unsigned short* __restrict__ Qhi,
                                                 unsigned short* __restrict__ Qlo,
                                                 unsigned short* __restrict__ Mhi,
                                                 unsigned short* __restrict__ Mlo,
                                                 unsigned short* __restrict__ Mpv2) {
    __shared__ __align__(16) float xs[32][128];          // 16 KB
    __shared__ __align__(8) unsigned short vstage[32][128];  // 8 KB

    const int b    = blockIdx.x >> 7;
    const int p7   = blockIdx.x & 127;
    const int t    = threadIdx.x;
    const int half = t >> 7;          // waves 0-1: k, waves 2-3: v
    const int u    = t & 127;
    const int q    = u & 31;          // channel group (cg) 0..31
    const int rg   = u >> 5;          // J-block: rows 8rg..8rg+7
    const int woff = 128 + (half << 7) + (q << 2);

    // stage x rows (coalesced float4)
    {
        const float* xb = x + ((size_t)(b * SEQ + p7)) * 128;
#pragma unroll
        for (int uu = 0; uu < 4; ++uu) {
            int idx = t + (uu << 8);               // 0..1023
            int j   = idx >> 5;
            int c4  = idx & 31;
            *(float4*)&xs[j][c4 * 4] =
                *(const float4*)(xb + (size_t)j * (128 * 128) + c4 * 4);
        }
    }
    __syncthreads();

    float acc[8][4];
#pragma unroll
    for (int jr = 0; jr < 8; ++jr)
#pragma unroll
        for (int a = 0; a < 4; ++a) acc[jr][a] = 0.f;

    // depth-1 prefetch pipeline on the w-tiles (static A/B register sets)
    float4 wA[4], wB[4];
#pragma unroll
    for (int i = 0; i < 4; ++i)
        wA[i] = *(const float4*)(wqkv + (size_t)i * 384 + woff);

    auto gstep = [&](float4 (&wcur)[4], float4 (&wnxt)[4], int i4) {
        const int i4n = (i4 + 4) & 127;            // wraps harmlessly on last
#pragma unroll
        for (int i = 0; i < 4; ++i)
            wnxt[i] = *(const float4*)(wqkv + (size_t)(i4n + i) * 384 + woff);
#pragma unroll
        for (int jr = 0; jr < 8; ++jr) {
            float4 xv = *(const float4*)&xs[8 * rg + jr][i4];
            acc[jr][0] = fmaf(xv.x, wcur[0].x, acc[jr][0]);
            acc[jr][1] = fmaf(xv.x, wcur[0].y, acc[jr][1]);
            acc[jr][2] = fmaf(xv.x, wcur[0].z, acc[jr][2]);
            acc[jr][3] = fmaf(xv.x, wcur[0].w, acc[jr][3]);
            acc[jr][0] = fmaf(xv.y, wcur[1].x, acc[jr][0]);
            acc[jr][1] = fmaf(xv.y, wcur[1].y, acc[jr][1]);
            acc[jr][2] = fmaf(xv.y, wcur[1].z, acc[jr][2]);
            acc[jr][3] = fmaf(xv.y, wcur[1].w, acc[jr][3]);
            acc[jr][0] = fmaf(xv.z, wcur[2].x, acc[jr][0]);
            acc[jr][1] = fmaf(xv.z, wcur[2].y, acc[jr][1]);
            acc[jr][2] = fmaf(xv.z, wcur[2].z, acc[jr][2]);
            acc[jr][3] = fmaf(xv.z, wcur[2].w, acc[jr][3]);
            acc[jr][0] = fmaf(xv.w, wcur[3].x, acc[jr][0]);
            acc[jr][1] = fmaf(xv.w, wcur[3].y, acc[jr][1]);
            acc[jr][2] = fmaf(xv.w, wcur[3].z, acc[jr][2]);
            acc[jr][3] = fmaf(xv.w, wcur[3].w, acc[jr][3]);
        }
    };
    for (int i4 = 0; i4 < 128; i4 += 8) {
        gstep(wA, wB, i4);
        gstep(wB, wA, i4 + 4);
    }

    const int pairbase = b << 2;
    const int de = (p7 << 5) + q;

    if (half == 0) {
        float qn[8][4];
#pragma unroll
        for (int jr = 0; jr < 8; ++jr) {
            float s = acc[jr][0] * acc[jr][0] + acc[jr][1] * acc[jr][1]
                    + acc[jr][2] * acc[jr][2] + acc[jr][3] * acc[jr][3];
            float inv = 14.426950408889634f / fmaxf(sqrtf(s), 1e-12f);
#pragma unroll
            for (int a = 0; a < 4; ++a) qn[jr][a] = acc[jr][a] * inv;
        }
#pragma unroll
        for (int a = 0; a < 4; ++a) {
            unsigned hi[4], lo[4];
#pragma unroll
            for (int j2 = 0; j2 < 4; ++j2) {
                float v0 = qn[2 * j2][a], v1 = qn[2 * j2 + 1][a];
                unsigned short h0 = f2bf(v0), h1 = f2bf(v1);
                hi[j2] = (unsigned)h0 | ((unsigned)h1 << 16);
                lo[j2] = (unsigned)f2bf(v0 - bf2f(h0))
                       | ((unsigned)f2bf(v1 - bf2f(h1)) << 16);
            }
            size_t off = (size_t)(pairbase + a) * PAIR_ELEMS + (size_t)de * 32 + 8 * rg;
            *(uint4*)(Qhi + off) = make_uint4(hi[0], hi[1], hi[2], hi[3]);
            *(uint4*)(Qlo + off) = make_uint4(lo[0], lo[1], lo[2], lo[3]);
        }
    } else {
#pragma unroll
        for (int a = 0; a < 4; ++a) {
            unsigned hi[4], lo[4];
#pragma unroll
            for (int j2 = 0; j2 < 4; ++j2) {
                float v0 = acc[2 * j2][a], v1 = acc[2 * j2 + 1][a];
                unsigned short h0 = f2bf(v0), h1 = f2bf(v1);
                hi[j2] = (unsigned)h0 | ((unsigned)h1 << 16);
                lo[j2] = (unsigned)f2bf(v0 - bf2f(h0))
                       | ((unsigned)f2bf(v1 - bf2f(h1)) << 16);
            }
            size_t off = (size_t)(pairbase + a) * PAIR_ELEMS + (size_t)de * 32 + 8 * rg;
            *(uint4*)(Mhi + off) = make_uint4(hi[0], hi[1], hi[2], hi[3]);
            *(uint4*)(Mlo + off) = make_uint4(lo[0], lo[1], lo[2], lo[3]);
        }
#pragma unroll
        for (int jr = 0; jr < 8; ++jr) {
            unsigned short h0 = f2bf(acc[jr][0]);
            unsigned short h1 = f2bf(acc[jr][1]);
            unsigned short h2 = f2bf(acc[jr][2]);
            unsigned short h3 = f2bf(acc[jr][3]);
            *(uint2*)&vstage[8 * rg + jr][4 * q] =
                make_uint2((unsigned)h0 | ((unsigned)h1 << 16),
                           (unsigned)h2 | ((unsigned)h3 << 16));
        }
    }
    __syncthreads();

    // Mpv2[pair][n=J][e''] scatter. e = 32*p7 + cg; within 64-block:
    // m=p7&1, h=cg>>4, g=(cg>>2)&3, r=cg&3 -> pos = 32m + 8g + 4h + r.
    // Pack cg=(2w, 2w+1) -> adjacent pos -> one u32:
    // u32 dst = pr*65536 + jj*2048 + (p7>>1)*32
    //         + (p7&1)*16 + ((w>>1)&3)*4 + (w>>3)*2 + (w&1)
    unsigned* mpv32 = (unsigned*)Mpv2;
#pragma unroll
    for (int uu = 0; uu < 8; ++uu) {
        int task = t + (uu << 8);                  // 2048 tasks
        int w  = task & 15;
        int jj = (task >> 4) & 31;
        int aa = task >> 9;
        unsigned lo = vstage[jj][(w << 3) + aa];        // cg = 2w
        unsigned hi = vstage[jj][(w << 3) + 4 + aa];    // cg = 2w+1
        int pr = (b << 2) + aa;
        size_t dst = (size_t)pr * 65536 + (size_t)jj * 2048
                   + ((size_t)(p7 >> 1)) * 32
                   + (size_t)((p7 & 1) * 16)
                   + (size_t)(((w >> 1) & 3) * 4)
                   + (size_t)((w >> 3) * 2)
                   + (size_t)(w & 1);
        mpv32[dst] = lo | (hi << 16);
    }
}

// ---------------------------------------------------------------------------
// Kernel 2: swapped-operand MFMA flash attention. 512 blocks x 4 waves x 32
// d-rows. No LDS, no barriers, no per-iter cross-lane ops. Depth-1 register
// prefetch of all 12 B-operand tiles. Lane (col,g) owns d = d0+16s+col.
// All MFMAs are 16x16x32 bf16 (the r2-r7-proven intrinsic).
// ---------------------------------------------------------------------------
__global__ __launch_bounds__(256, 2) void attn_kernel(const unsigned short* __restrict__ Qhi,
                                                      const unsigned short* __restrict__ Qlo,
                                                      const unsigned short* __restrict__ Mhi,
                                                      const unsigned short* __restrict__ Mlo,
                                                      const unsigned short* __restrict__ Mpv2,
                                                      unsigned short* __restrict__ outb) {
    const int bid  = blockIdx.x;                 // 512
    const int pair = ((bid & 7) << 1) + (bid >> 8);
    const int dblk = (bid & 255) >> 3;           // 0..31
    const int t    = threadIdx.x;
    const int wid  = t >> 6;
    const int lane = t & 63;
    const int col  = lane & 15;
    const int g    = lane >> 4;
    const int d0   = dblk * 128 + wid * 32;

    const size_t pb = (size_t)pair * PAIR_ELEMS;

    bf16x8 ah[2], al[2];
#pragma unroll
    for (int s = 0; s < 2; ++s) {
        size_t o = pb + (size_t)(d0 + 16 * s + col) * 32 + g * 8;
        ah[s] = *(const bf16x8*)(Qhi + o);
        al[s] = *(const bf16x8*)(Qlo + o);
    }

    const unsigned short* mh = Mhi + pb;
    const unsigned short* ml = Mlo + pb;
    const unsigned short* mp = Mpv2 + pb;        // [n:32][e'':4096]
    const f32x4 z = {0.f, 0.f, 0.f, 0.f};

    // ---- phase 1: exact per-d max of bf16 QK (swapped: sv = S^T frag)
    float rmax[2] = {-3e38f, -3e38f};
    {
        bf16x8 pA[4], pB[4];
#pragma unroll
        for (int cc = 0; cc < 4; ++cc)
            pA[cc] = *(const bf16x8*)(mh + (size_t)(16 * cc + col) * 32 + g * 8);

        auto sweep = [&](bf16x8 (&cur)[4], bf16x8 (&nxt)[4], int e0) {
            const int en = (e0 + 64) & (SEQ - 1);
#pragma unroll
            for (int cc = 0; cc < 4; ++cc)
                nxt[cc] = *(const bf16x8*)(mh + (size_t)(en + 16 * cc + col) * 32 + g * 8);
#pragma unroll
            for (int cc = 0; cc < 4; ++cc) {
#pragma unroll
                for (int s = 0; s < 2; ++s) {
                    f32x4 sv = __builtin_amdgcn_mfma_f32_16x16x32_bf16(cur[cc], ah[s], z, 0, 0, 0);
                    rmax[s] = fmaxf(rmax[s], fmaxf(fmaxf(sv[0], sv[1]), fmaxf(sv[2], sv[3])));
                }
            }
        };
        for (int e0 = 0; e0 < SEQ; e0 += 128) {
            sweep(pA, pB, e0);
            sweep(pB, pA, e0 + 64);
        }
    }
    // reduce over the 4 lanes sharing col (the g groups): xor16 + xor32
#pragma unroll
    for (int s = 0; s < 2; ++s) {
        float m = rmax[s];
        m = fmaxf(m, __shfl_xor(m, 16));
        m = fmaxf(m, __shfl_xor(m, 32));
        rmax[s] = m;
    }
    f32x4 minit[2];
#pragma unroll
    for (int s = 0; s < 2; ++s)
        minit[s] = (f32x4){-rmax[s], -rmax[s], -rmax[s], -rmax[s]};

    f32x4 O[2][2];   // [s][nh]: O[d=d0+16s+col][n=16nh+4g+r]
    float lsum[2] = {0.f, 0.f};
#pragma unroll
    for (int s = 0; s < 2; ++s)
#pragma unroll
        for (int nh = 0; nh < 2; ++nh) O[s][nh] = (f32x4){0.f, 0.f, 0.f, 0.f};

    // ---- phase 2: main flash loop.
    // cur[0..3]=Mhi(cc), [4..7]=Mlo(cc), [8+2*nh+m]=Mpv2 A-frag (m: e-half)
    {
        bf16x8 tA[12], tB[12];
#pragma unroll
        for (int cc = 0; cc < 4; ++cc) {
            size_t ro = (size_t)(16 * cc + col) * 32 + g * 8;
            tA[cc]     = *(const bf16x8*)(mh + ro);
            tA[4 + cc] = *(const bf16x8*)(ml + ro);
        }
#pragma unroll
        for (int nh = 0; nh < 2; ++nh)
#pragma unroll
            for (int m = 0; m < 2; ++m)
                tA[8 + 2 * nh + m] =
                    *(const bf16x8*)(mp + (size_t)(16 * nh + col) * SEQ + 32 * m + 8 * g);

        auto flash = [&](bf16x8 (&cur)[12], bf16x8 (&nxt)[12], int e0) {
            const int en = (e0 + 64) & (SEQ - 1);
            // prefetch next tile (issued before any use of cur)
#pragma unroll
            for (int cc = 0; cc < 4; ++cc) {
                size_t ro = (size_t)(en + 16 * cc + col) * 32 + g * 8;
                nxt[cc]     = *(const bf16x8*)(mh + ro);
                nxt[4 + cc] = *(const bf16x8*)(ml + ro);
            }
#pragma unroll
            for (int nh = 0; nh < 2; ++nh)
#pragma unroll
                for (int m = 0; m < 2; ++m)
                    nxt[8 + 2 * nh + m] =
                        *(const bf16x8*)(mp + (size_t)(16 * nh + col) * SEQ
                                         + en + 32 * m + 8 * g);

            // S^T = M * Q^T (hi/lo split, C-init = -max): lane (col,g) holds
            // S[d=d0+16s+col][e=e0+16cc+4g+r]
            f32x4 S[2][4];
#pragma unroll
            for (int cc = 0; cc < 4; ++cc) {
#pragma unroll
                for (int s = 0; s < 2; ++s) {
                    f32x4 tac = __builtin_amdgcn_mfma_f32_16x16x32_bf16(cur[4 + cc], ah[s], minit[s], 0, 0, 0);
                    tac = __builtin_amdgcn_mfma_f32_16x16x32_bf16(cur[cc], al[s], tac, 0, 0, 0);
                    S[s][cc] = __builtin_amdgcn_mfma_f32_16x16x32_bf16(cur[cc], ah[s], tac, 0, 0, 0);
                }
            }
            // P = exp2(S) -> bf16 u32 pairs (per-lane, no cross-lane movement)
            unsigned pw[2][4][2];
#pragma unroll
            for (int s = 0; s < 2; ++s) {
#pragma unroll
                for (int cc = 0; cc < 4; ++cc) {
                    float p0 = __builtin_amdgcn_exp2f(S[s][cc][0]);
                    float p1 = __builtin_amdgcn_exp2f(S[s][cc][1]);
                    float p2 = __builtin_amdgcn_exp2f(S[s][cc][2]);
                    float p3 = __builtin_amdgcn_exp2f(S[s][cc][3]);
                    lsum[s] += (p0 + p1) + (p2 + p3);
                    asm("v_cvt_pk_bf16_f32 %0, %1, %2" : "=v"(pw[s][cc][0]) : "v"(p0), "v"(p1));
                    asm("v_cvt_pk_bf16_f32 %0, %1, %2" : "=v"(pw[s][cc][1]) : "v"(p2), "v"(p3));
                }
            }
            // O^T += M^T * P via 16x16x32 MFMAs.
            // B-frag (k=8g+i <-> e = e0+32m+16(i>>2)+4g+(i&3)) = concat of
            // pp[2m], pp[2m+1]; A-frag = Mpv2 tile (matching e-perm).
#pragma unroll
            for (int s = 0; s < 2; ++s) {
#pragma unroll
                for (int m = 0; m < 2; ++m) {
                    unsigned pk4[4] = {pw[s][2 * m][0], pw[s][2 * m][1],
                                       pw[s][2 * m + 1][0], pw[s][2 * m + 1][1]};
                    bf16x8 pbf = *(bf16x8*)pk4;
                    O[s][0] = __builtin_amdgcn_mfma_f32_16x16x32_bf16(cur[8 + 0 + m], pbf, O[s][0], 0, 0, 0);
                    O[s][1] = __builtin_amdgcn_mfma_f32_16x16x32_bf16(cur[8 + 2 + m], pbf, O[s][1], 0, 0, 0);
                }
            }
        };
        for (int e0 = 0; e0 < SEQ; e0 += 128) {
            flash(tA, tB, e0);
            flash(tB, tA, e0 + 64);
        }
    }

    // ---- final l reduce (lanes sharing col)
#pragma unroll
    for (int s = 0; s < 2; ++s) {
        float l = lsum[s];
        l += __shfl_xor(l, 16);
        l += __shfl_xor(l, 32);
        lsum[s] = l;
    }

    // ---- epilogue: outb[b][d][n*4+a], d = d0+16s+col, n = 16nh+4g+r
    const int bb = pair >> 2;
    const int aa = pair & 3;
#pragma unroll
    for (int s = 0; s < 2; ++s) {
        float inv = 1.0f / lsum[s];
        size_t rowb = ((size_t)(bb * SEQ + d0 + 16 * s + col)) * 128;
#pragma unroll
        for (int nh = 0; nh < 2; ++nh) {
#pragma unroll
            for (int r = 0; r < 4; ++r) {
                int n = 16 * nh + 4 * g + r;
                outb[rowb + n * 4 + aa] = f2bf(O[s][nh][r] * inv);
            }
        }
    }
}

// ---------------------------------------------------------------------------
// Kernel 3: y = opre(bf16) @ w_out + b_out  (fp32 vector GEMM) — unchanged
// ---------------------------------------------------------------------------
__global__ __launch_bounds__(256) void out_kernel(const unsigned short* __restrict__ opre,
                                                  const float* __restrict__ wout,
                                                  const float* __restrict__ bout,
                                                  float* __restrict__ y) {
    __shared__ __align__(16) float xs[8][128];
    const int r0 = blockIdx.x * 8;
    const int t  = threadIdx.x;
    {
        const unsigned* src = (const unsigned*)(opre + (size_t)r0 * 128);
        unsigned v0 = src[t * 2], v1 = src[t * 2 + 1];
        float* dst = &xs[0][0] + t * 4;
        dst[0] = bf2f((unsigned short)(v0 & 0xffff));
        dst[1] = bf2f((unsigned short)(v0 >> 16));
        dst[2] = bf2f((unsigned short)(v1 & 0xffff));
        dst[3] = bf2f((unsigned short)(v1 >> 16));
    }
    __syncthreads();

    const int c  = t & 127;
    const int rh = (t >> 7) * 4;
    float acc[4] = {0.f, 0.f, 0.f, 0.f};

    for (int i = 0; i < 128; i += 4) {
        float w0 = wout[(i + 0) * 128 + c];
        float w1 = wout[(i + 1) * 128 + c];
        float w2 = wout[(i + 2) * 128 + c];
        float w3 = wout[(i + 3) * 128 + c];
#pragma unroll
        for (int p = 0; p < 4; ++p) {
            float4 xp = *(const float4*)&xs[rh + p][i];
            acc[p] = fmaf(xp.x, w0, acc[p]);
            acc[p] = fmaf(xp.y, w1, acc[p]);
            acc[p] = fmaf(xp.z, w2, acc[p]);
            acc[p] = fmaf(xp.w, w3, acc[p]);
        }
    }
    float bb = bout[c];
#pragma unroll
    for (int p = 0; p < 4; ++p) {
        y[((size_t)(r0 + rh + p)) * 128 + c] = acc[p] + bb;
    }
}

// ---------------------------------------------------------------------------
extern "C" void kernel_launch(void* const* d_in, const int* in_sizes, int n_in,
                              void* d_out, int out_size, void* d_ws, size_t ws_size,
                              hipStream_t stream) {
    const float* x    = (const float*)d_in[0];
    const float* wqkv = (const float*)d_in[1];
    const float* wout = (const float*)d_in[2];
    const float* bout = (const float*)d_in[3];
    float* y = (float*)d_out;

    unsigned short* Qhi = (unsigned short*)d_ws;
    unsigned short* Qlo = Qhi + (size_t)16 * PAIR_ELEMS;
    unsigned short* Mhi = Qlo + (size_t)16 * PAIR_ELEMS;
    unsigned short* Mlo = Mhi + (size_t)16 * PAIR_ELEMS;
    unsigned short* Mpv2 = Mlo + (size_t)16 * PAIR_ELEMS;
    unsigned short* outb = Mpv2 + (size_t)16 * PAIR_ELEMS;

    kv_kernel<<<512, 256, 0, stream>>>(x, wqkv, Qhi, Qlo, Mhi, Mlo, Mpv2);
    attn_kernel<<<512, 256, 0, stream>>>(Qhi, Qlo, Mhi, Mlo, Mpv2, outb);
    out_kernel<<<2048, 256, 0, stream>>>(outb, wout, bout, y);
}